// Round 5
// baseline (201.433 us; speedup 1.0000x reference)
//
#include <hip/hip_runtime.h>

#define DIM   256
#define HALF  128
#define F0    10
#define F1    25
#define B0    1024
#define M1    10240            // B0 * F0
#define TASKS (M1 + B0)        // 11264 aggregate rows total

typedef __attribute__((ext_vector_type(8))) short bf16x8;  // 8 bf16 = 4 VGPRs
typedef __attribute__((ext_vector_type(4))) float f32x4;

#define LSTRIDE 264   // LDS row stride in bf16 elems (528 B, 16B multiple)

__device__ __forceinline__ unsigned short f2bf(float x) {
    union { float f; unsigned u; } v; v.f = x;
    unsigned r = v.u + 0x7fffu + ((v.u >> 16) & 1u);   // RNE
    return (unsigned short)(r >> 16);
}
__device__ __forceinline__ float bf2f(unsigned short b) {
    union { unsigned u; float f; } v; v.u = ((unsigned)b) << 16;
    return v.f;
}
__device__ __forceinline__ uint2 pack4(float a, float b, float c, float d) {
    uint2 p;
    p.x = (unsigned)f2bf(a) | ((unsigned)f2bf(b) << 16);
    p.y = (unsigned)f2bf(c) | ((unsigned)f2bf(d) << 16);
    return p;
}

// ---------- Prep: W0_{self,neigh} -> bf16 B-fragments in frag-linear order.
__global__ __launch_bounds__(64) void prep_w(
    const float* __restrict__ Ws,
    const float* __restrict__ Wn,
    unsigned short* __restrict__ bfrag)
{
    const int bx   = blockIdx.x;       // [0,128)
    const int mat  = bx >> 6;
    const int f    = bx & 63;          // t*8+kk
    const int t    = f >> 3, kk = f & 7;
    const int lane = threadIdx.x;
    const int n    = lane & 15, q = lane >> 4;
    const float* W = mat ? Wn : Ws;

    __align__(16) unsigned short tmp[8];
    #pragma unroll
    for (int j = 0; j < 8; ++j)
        tmp[j] = f2bf(W[(kk * 32 + q * 8 + j) * HALF + t * 16 + n]);
    *(uint4*)(bfrag + ((size_t)(mat * 64 + f) * 64 + lane) * 8) = *(const uint4*)tmp;
}

// ---------- Kernel A: pure gather + mean. One WAVE per aggregate row.
// Tasks [0, M1): hop1 (self=sn1[r], neigh=sn2[r*25..]) ; [M1, TASKS): hop0.
// Output: staged[task][0..255]=self bf16, [256..511]=mean bf16. No LDS, no barrier.
template<int NF>
__device__ __forceinline__ void gather_row(
    const float* __restrict__ feat,
    const int*   __restrict__ selfIdx,
    const int*   __restrict__ neighIdx,
    int r, int lane,
    unsigned short* __restrict__ dstrow)
{
    const int si = selfIdx[r];                         // wave-uniform scalar load
    const float4 sv = *(const float4*)(feat + (size_t)si * DIM + lane * 4);
    *(uint2*)(dstrow + lane * 4) = pack4(sv.x, sv.y, sv.z, sv.w);

    float4 a = make_float4(0.f, 0.f, 0.f, 0.f);
    #pragma unroll
    for (int j = 0; j < NF; ++j) {
        const int gi = neighIdx[r * NF + j];           // wave-uniform scalar load
        const float4 v = *(const float4*)(feat + (size_t)gi * DIM + lane * 4);
        a.x += v.x; a.y += v.y; a.z += v.z; a.w += v.w;
    }
    const float sc = 1.0f / (float)NF;
    *(uint2*)(dstrow + DIM + lane * 4) = pack4(a.x * sc, a.y * sc, a.z * sc, a.w * sc);
}

__global__ __launch_bounds__(256, 8) void sage_gather(
    const float* __restrict__ feat,
    const int*   __restrict__ sn0,
    const int*   __restrict__ sn1,
    const int*   __restrict__ sn2,
    unsigned short* __restrict__ staged)
{
    const int wv   = __builtin_amdgcn_readfirstlane(threadIdx.x >> 6);
    const int lane = threadIdx.x & 63;
    const int task = blockIdx.x * 4 + wv;
    unsigned short* dstrow = staged + (size_t)task * (2 * DIM);

    if (task < M1) {
        gather_row<F1>(feat, sn1, sn2, task, lane, dstrow);
    } else {
        gather_row<F0>(feat, sn0, sn1, task - M1, lane, dstrow);
    }
}

// ---------- Kernel B: streaming MFMA transform of staged rows.
// Blocks [0, 640): hop1 -> n1 bf16 ; [640, 704): hop0 -> n0 fp32 (d_out scratch).
__global__ __launch_bounds__(512, 4) void sage_mm(
    const unsigned short* __restrict__ staged,
    const unsigned short* __restrict__ bfrag,
    float*          __restrict__ n0,
    unsigned short* __restrict__ n1)
{
    __shared__ __align__(16) unsigned short sh[2][16][LSTRIDE];  // [self|agg][row][dim]

    const int tid  = threadIdx.x;
    const int gb   = blockIdx.x;
    const bool hop0 = (gb >= M1 / 16);
    const int srow = gb * 16;                 // staged row base (hop0 rows live at [M1, TASKS))

    // stage 16 rows x 512 bf16 = 16 KB, coalesced uint2 chunks.
    for (int i = tid; i < 16 * 128; i += 512) {
        const int r = i >> 7, s = i & 127;    // s: 128 uint2 chunks of 4 bf16
        *(uint2*)(&sh[s >> 6][r][(s & 63) * 4]) =
            *(const uint2*)(staged + (size_t)(srow + r) * (2 * DIM) + s * 4);
    }
    __syncthreads();

    // ---- MFMA: wave wv -> half h = wv>>2, tiles t0=(wv&3)*2, t0+1.
    const int wv   = __builtin_amdgcn_readfirstlane(tid >> 6);
    const int lane = tid & 63;
    const int h    = wv >> 2;
    const int t0   = (wv & 3) * 2;
    const int m    = lane & 15;
    const int q    = lane >> 4;

    f32x4 acc0 = {0.f, 0.f, 0.f, 0.f};
    f32x4 acc1 = {0.f, 0.f, 0.f, 0.f};

    #pragma unroll
    for (int kk = 0; kk < 8; ++kk) {
        const bf16x8 af = *(const bf16x8*)(&sh[h][m][kk * 32 + q * 8]);
        const bf16x8 b0 = *(const bf16x8*)(bfrag + ((size_t)(h * 64 + (t0 + 0) * 8 + kk) * 64 + lane) * 8);
        const bf16x8 b1 = *(const bf16x8*)(bfrag + ((size_t)(h * 64 + (t0 + 1) * 8 + kk) * 64 + lane) * 8);
        acc0 = __builtin_amdgcn_mfma_f32_16x16x32_bf16(af, b0, acc0, 0, 0, 0);
        acc1 = __builtin_amdgcn_mfma_f32_16x16x32_bf16(af, b1, acc1, 0, 0, 0);
    }

    // ---- epilogue: C/D layout col = lane&15, row = q*4 + reg. ReLU.
    const int orow_base = hop0 ? (srow - M1) : srow;
    #pragma unroll
    for (int reg = 0; reg < 4; ++reg) {
        const int row  = orow_base + q * 4 + reg;
        const int col0 = h * HALF + (t0 + 0) * 16 + m;
        const int col1 = h * HALF + (t0 + 1) * 16 + m;
        const float v0 = fmaxf(acc0[reg], 0.f);
        const float v1 = fmaxf(acc1[reg], 0.f);
        if (hop0) {
            n0[(size_t)row * DIM + col0] = v0;
            n0[(size_t)row * DIM + col1] = v1;
        } else {
            n1[(size_t)row * DIM + col0] = f2bf(v0);
            n1[(size_t)row * DIM + col1] = f2bf(v1);
        }
    }
}

// ---------- Final layer: out = concat(n0 @ W1s, mean10(n1) @ W1n), fp32 VALU.
#define PAD 260
#define R2  4

__global__ __launch_bounds__(256) void sage_final(
    const unsigned short* __restrict__ n1,
    const float* __restrict__ W1s,
    const float* __restrict__ W1n,
    float*       out)              // aliases n0 input — no restrict
{
    __shared__ float sh_n0 [R2][PAD];
    __shared__ float sh_agg[R2][PAD];

    const int tid     = threadIdx.x;
    const int rowbase = blockIdx.x * R2;
    const int wave    = tid >> 6;
    const int lane    = tid & 63;

    {
        const int r = wave;
        *(float4*)(&sh_n0[r][lane * 4]) =
            *(const float4*)(out + (size_t)(rowbase + r) * DIM + lane * 4);

        const unsigned short* base = n1 + ((size_t)(rowbase + r) * F0) * DIM + lane * 4;
        float4 a = make_float4(0.f, 0.f, 0.f, 0.f);
        #pragma unroll
        for (int j = 0; j < F0; ++j) {
            const uint2 p = *(const uint2*)(base + (size_t)j * DIM);
            a.x += bf2f((unsigned short)(p.x & 0xffff));
            a.y += bf2f((unsigned short)(p.x >> 16));
            a.z += bf2f((unsigned short)(p.y & 0xffff));
            a.w += bf2f((unsigned short)(p.y >> 16));
        }
        const float sc = 1.0f / (float)F0;
        a.x *= sc; a.y *= sc; a.z *= sc; a.w *= sc;
        *(float4*)(&sh_agg[r][lane * 4]) = a;
    }
    __syncthreads();

    const int  u     = tid & 127;
    const int  c0    = u * 2;
    const int  rb    = (tid >> 7) * 2;
    const bool neigh = (c0 >= HALF);
    const float* __restrict__ W = neigh ? W1n : W1s;
    const int  col   = neigh ? (c0 - HALF) : c0;
    const float (*src)[PAD] = neigh ? sh_agg : sh_n0;

    float a0[2] = {0.f, 0.f}, a1[2] = {0.f, 0.f};
    for (int d = 0; d < DIM; d += 4) {
        const float2 w0 = *(const float2*)(W + (d + 0) * HALF + col);
        const float2 w1 = *(const float2*)(W + (d + 1) * HALF + col);
        const float2 w2 = *(const float2*)(W + (d + 2) * HALF + col);
        const float2 w3 = *(const float2*)(W + (d + 3) * HALF + col);
        #pragma unroll
        for (int r = 0; r < 2; ++r) {
            const float4 hh = *(const float4*)(&src[rb + r][d]);
            a0[r] += hh.x * w0.x + hh.y * w1.x + hh.z * w2.x + hh.w * w3.x;
            a1[r] += hh.x * w0.y + hh.y * w1.y + hh.z * w2.y + hh.w * w3.y;
        }
    }

    #pragma unroll
    for (int r = 0; r < 2; ++r) {
        float2 o;
        o.x = a0[r];
        o.y = a1[r];
        *(float2*)(out + (size_t)(rowbase + rb + r) * DIM + c0) = o;
    }
}

extern "C" void kernel_launch(void* const* d_in, const int* in_sizes, int n_in,
                              void* d_out, int out_size, void* d_ws, size_t ws_size,
                              hipStream_t stream) {
    (void)in_sizes; (void)n_in; (void)out_size; (void)ws_size;
    const float* feat = (const float*)d_in[0];
    const int*   sn0  = (const int*)  d_in[1];
    const int*   sn1  = (const int*)  d_in[2];
    const int*   sn2  = (const int*)  d_in[3];
    const float* W0s  = (const float*)d_in[4];
    const float* W0n  = (const float*)d_in[5];
    const float* W1s  = (const float*)d_in[6];
    const float* W1n  = (const float*)d_in[7];
    float* out = (float*)d_out;

    // ws layout (all 16B-aligned):
    //   [0, 5 MB)          n1 bf16                  10240*256*2 = 5,242,880
    //   [5 MB, 16.5 MB)    staged self|agg bf16     11264*512*2 = 11,534,336
    //   [16.5 MB, +128 KB) W0 B-fragments           131,072
    unsigned short* n1     = (unsigned short*)d_ws;
    unsigned short* staged = (unsigned short*)((char*)d_ws + 5242880);
    unsigned short* bfrag  = (unsigned short*)((char*)d_ws + 5242880 + 11534336);

    prep_w     <<<128, 64, 0, stream>>>(W0s, W0n, bfrag);
    sage_gather<<<TASKS / 4, 256, 0, stream>>>(feat, sn0, sn1, sn2, staged);
    sage_mm    <<<TASKS / 16, 512, 0, stream>>>(staged, bfrag, out, n1);
    sage_final <<<B0 / R2, 256, 0, stream>>>(n1, W1s, W1n, out);
}